// Round 5
// baseline (1287.453 us; speedup 1.0000x reference)
//
#include <hip/hip_runtime.h>
#include <math.h>

// ---------------------------------------------------------------------------
// Temporal GNN. Round 12:
//  * tg_agg_gemm rewritten BARRIER-FREE: each wave owns 16 rows; gathers
//    them into a private 8KB XOR-swizzled LDS strip, then GEMMs its 16x256
//    strip with B read straight from global (Bt 512KB, L2-resident -> no
//    L3-fabric competition with the gather). Zero __syncthreads -> waves
//    stagger naturally; fabric stays saturated while other waves MFMA.
//    Cross-lane LDS handoff fenced per-wave (lgkmcnt(0)+sched_barrier).
//    A-frags reused across Bh/Bl. Accumulation order identical to r11.
//  * Everything else unchanged from round 11.
// ---------------------------------------------------------------------------

typedef __attribute__((ext_vector_type(8))) _Float16 half8;  // MFMA A/B frag
typedef __attribute__((ext_vector_type(4))) float floatx4;   // MFMA C/D
typedef __attribute__((ext_vector_type(8))) unsigned short us8; // 16B f16 vec

union HU { _Float16 h; unsigned short u; };

static __device__ __forceinline__ unsigned short f2h(float f) {
    HU x; x.h = (_Float16)f; return x.u;          // v_cvt_f16_f32 (RNE)
}
static __device__ __forceinline__ float h2f(unsigned short s) {
    HU x; x.u = s; return (float)x.h;
}

// async 16B/lane global -> LDS (dest = wave-uniform base + lane*16)
static __device__ __forceinline__ void gl_lds16(const void* g, void* l) {
    __builtin_amdgcn_global_load_lds(
        (const __attribute__((address_space(1))) unsigned int*)(g),
        (__attribute__((address_space(3))) unsigned int*)(l), 16, 0, 0);
}

// sin/cos(ang) for ang up to ~1e5 rad: Cody-Waite 3-term reduction
// + hardware trig on revolutions.
static __device__ __forceinline__ float cw_trig(float ang, bool is_cos) {
    const float i2pi = 0.15915494309189535f;
    const float k = rintf(ang * i2pi);
    float r = fmaf(k, -6.28125f, ang);
    r = fmaf(k, -1.9352436065673828e-3f, r);
    r = fmaf(k, -6.3573019e-8f, r);
    const float rv = r * i2pi;
    return is_cos ? __builtin_amdgcn_cosf(rv) : __builtin_amdgcn_sinf(rv);
}

// Split W[256][256] (k-major) into Bt'[n][512] = [Bh | Bl] f16 (transposed).
__global__ void tg_splitB(const float* __restrict__ W0, const float* __restrict__ W1,
                          const float* __restrict__ W2, const float* __restrict__ W3,
                          unsigned short* __restrict__ B0, unsigned short* __restrict__ B1,
                          unsigned short* __restrict__ B2, unsigned short* __restrict__ B3)
{
    const float* Ws[4] = {W0, W1, W2, W3};
    unsigned short* Bs[4] = {B0, B1, B2, B3};
    const float* W = Ws[blockIdx.z];
    unsigned short* Bt = Bs[blockIdx.z];

    __shared__ float T[64][68];
    const int tk = blockIdx.x * 64, tn = blockIdx.y * 64;
    const int t = threadIdx.x;
#pragma unroll
    for (int j = 0; j < 4; ++j) {
        const int idx = t + 256 * j;
        const int k = idx >> 4, c4 = (idx & 15) * 4;
        const float4 v = *(const float4*)&W[(size_t)(tk + k) * 256 + tn + c4];
        T[k][c4] = v.x; T[k][c4 + 1] = v.y; T[k][c4 + 2] = v.z; T[k][c4 + 3] = v.w;
    }
    __syncthreads();
#pragma unroll
    for (int j = 0; j < 4; ++j) {
        const int idx = t + 256 * j;
        const int n = idx >> 4, q = (idx & 15) * 4;
        unsigned short hh[4], ll[4];
#pragma unroll
        for (int i = 0; i < 4; ++i) {
            const float f = T[q + i][n];
            hh[i] = f2h(f);
            ll[i] = f2h(f - h2f(hh[i]));
        }
        uint2 hp, lp;
        hp.x = (unsigned)hh[0] | ((unsigned)hh[1] << 16);
        hp.y = (unsigned)hh[2] | ((unsigned)hh[3] << 16);
        lp.x = (unsigned)ll[0] | ((unsigned)ll[1] << 16);
        lp.y = (unsigned)ll[2] | ((unsigned)ll[3] << 16);
        unsigned short* row = Bt + (size_t)(tn + n) * 512;
        *(uint2*)&row[tk + q]       = hp;   // Bh
        *(uint2*)&row[256 + tk + q] = lp;   // Bl
    }
}

// ---------------------------------------------------------------------------
// Fused FT GEMM + LayerNorm + PE (round-10 structure, unchanged).
// ---------------------------------------------------------------------------
__global__ __launch_bounds__(256, 2)
void tg_ft_ln(const float* __restrict__ x, const unsigned short* __restrict__ Bt,
              const float* __restrict__ bias, const float* __restrict__ lng,
              const float* __restrict__ lnb, unsigned short* __restrict__ hh, int N)
{
    __shared__ unsigned short sAh[128 * 64];   // 16 KB
    __shared__ unsigned short sAl[128 * 64];   // 16 KB
    __shared__ unsigned short sB[256 * 64];    // 32 KB (Bh then Bl)
    __shared__ float sStats[128][2][2];        // [row][wc][{sum,sumsq}] 2 KB
    __shared__ float sDiv[128];                // PE div table (512 B)

    const int t = threadIdx.x;
    const int w = t >> 6, lane = t & 63;
    const int quad = lane >> 4, l16 = lane & 15;
    const int wr = w >> 1, wc = w & 1;
    const int row0 = blockIdx.x * 128;

    if (t < 128) sDiv[t] = expf((float)(2 * t) * -0.035977892078031970f);

    floatx4 acc[4][8];
#pragma unroll
    for (int i = 0; i < 4; ++i)
#pragma unroll
        for (int j = 0; j < 8; ++j) acc[i][j] = (floatx4){0.f, 0.f, 0.f, 0.f};

    const int arow = t >> 1;
    const int ahalf = t & 1;
    const int srow = lane >> 3;
    const int kgx  = (lane & 7) ^ srow;
    const int rsw  = l16 & 7;

    for (int k4 = 0; k4 < 4; ++k4) {
        const int ka = k4 * 64;
        if (k4) __syncthreads();
        // issue sB = Bh(ka) first (async, overlaps the A chain)
#pragma unroll
        for (int i = 0; i < 8; ++i) {
            const int rr = w * 64 + i * 8;
            gl_lds16(Bt + (size_t)(rr + srow) * 512 + ka + kgx * 8, &sB[rr * 64]);
        }
        // stage A: read f32 x, split to hi/lo f16, swizzled ds_write
        {
            const int grow = row0 + arow;
            const bool ok = grow < N;
            const float* xp = x + (size_t)grow * 256 + ka + ahalf * 32;
#pragma unroll
            for (int j = 0; j < 4; ++j) {
                const int kg = ahalf * 4 + j;
                float4 v0 = {0.f, 0.f, 0.f, 0.f}, v1 = {0.f, 0.f, 0.f, 0.f};
                if (ok) {
                    v0 = *(const float4*)(xp + j * 8);
                    v1 = *(const float4*)(xp + j * 8 + 4);
                }
                const float f[8] = {v0.x, v0.y, v0.z, v0.w, v1.x, v1.y, v1.z, v1.w};
                us8 hi, lo;
#pragma unroll
                for (int i = 0; i < 8; ++i) {
                    hi[i] = f2h(f[i]);
                    lo[i] = f2h(f[i] - h2f(hi[i]));
                }
                const int ad = arow * 64 + ((kg ^ (arow & 7)) << 3);
                *(us8*)&sAh[ad] = hi;
                *(us8*)&sAl[ad] = lo;
            }
        }
        __syncthreads();
        // P0 + P1: Ah.Bh + Al.Bh
#pragma unroll
        for (int ks = 0; ks < 2; ++ks) {
            const int kq = ks * 4 + quad;
            half8 afh[4], afl[4];
#pragma unroll
            for (int rt = 0; rt < 4; ++rt) {
                const int r = wr * 64 + rt * 16 + l16;
                const int off = r * 64 + ((kq ^ rsw) << 3);
                afh[rt] = *(const half8*)&sAh[off];
                afl[rt] = *(const half8*)&sAl[off];
            }
#pragma unroll
            for (int cb = 0; cb < 2; ++cb) {
                half8 bfr[4];
#pragma unroll
                for (int c4 = 0; c4 < 4; ++c4) {
                    const int n = wc * 128 + (cb * 4 + c4) * 16 + l16;
                    bfr[c4] = *(const half8*)&sB[n * 64 + ((kq ^ rsw) << 3)];
                }
#pragma unroll
                for (int c4 = 0; c4 < 4; ++c4)
#pragma unroll
                    for (int rt = 0; rt < 4; ++rt) {
                        acc[rt][cb * 4 + c4] = __builtin_amdgcn_mfma_f32_16x16x32_f16(
                            afh[rt], bfr[c4], acc[rt][cb * 4 + c4], 0, 0, 0);
                        acc[rt][cb * 4 + c4] = __builtin_amdgcn_mfma_f32_16x16x32_f16(
                            afl[rt], bfr[c4], acc[rt][cb * 4 + c4], 0, 0, 0);
                    }
            }
        }
        __syncthreads();
        // stage sB = Bl(ka)
#pragma unroll
        for (int i = 0; i < 8; ++i) {
            const int rr = w * 64 + i * 8;
            gl_lds16(Bt + (size_t)(rr + srow) * 512 + 256 + ka + kgx * 8, &sB[rr * 64]);
        }
        __syncthreads();
        // P2: Ah.Bl
#pragma unroll
        for (int ks = 0; ks < 2; ++ks) {
            const int kq = ks * 4 + quad;
            half8 afh[4];
#pragma unroll
            for (int rt = 0; rt < 4; ++rt) {
                const int r = wr * 64 + rt * 16 + l16;
                afh[rt] = *(const half8*)&sAh[r * 64 + ((kq ^ rsw) << 3)];
            }
#pragma unroll
            for (int cb = 0; cb < 2; ++cb) {
                half8 bfr[4];
#pragma unroll
                for (int c4 = 0; c4 < 4; ++c4) {
                    const int n = wc * 128 + (cb * 4 + c4) * 16 + l16;
                    bfr[c4] = *(const half8*)&sB[n * 64 + ((kq ^ rsw) << 3)];
                }
#pragma unroll
                for (int c4 = 0; c4 < 4; ++c4)
#pragma unroll
                    for (int rt = 0; rt < 4; ++rt)
                        acc[rt][cb * 4 + c4] = __builtin_amdgcn_mfma_f32_16x16x32_f16(
                            afh[rt], bfr[c4], acc[rt][cb * 4 + c4], 0, 0, 0);
            }
        }
    }

    float bs[8], gs[8], bv[8], dv[8];
#pragma unroll
    for (int ct = 0; ct < 8; ++ct) {
        const int gc = wc * 128 + ct * 16 + l16;
        bs[ct] = bias[gc]; gs[ct] = lng[gc]; bv[ct] = lnb[gc];
        dv[ct] = sDiv[gc >> 1];
    }

#pragma unroll
    for (int rt = 0; rt < 4; ++rt) {
#pragma unroll
        for (int i = 0; i < 4; ++i) {
            float s = 0.f, q = 0.f;
#pragma unroll
            for (int ct = 0; ct < 8; ++ct) {
                const float v = fmaxf(acc[rt][ct][i] + bs[ct], 0.f);
                s += v; q += v * v;
            }
#pragma unroll
            for (int m = 1; m < 16; m <<= 1) {
                s += __shfl_xor(s, m, 64);
                q += __shfl_xor(q, m, 64);
            }
            if (l16 == 0) {
                const int rl = wr * 64 + rt * 16 + quad * 4 + i;
                sStats[rl][wc][0] = s;
                sStats[rl][wc][1] = q;
            }
        }
    }
    __syncthreads();

    const bool is_cos = (l16 & 1);
#pragma unroll
    for (int rt = 0; rt < 4; ++rt) {
#pragma unroll
        for (int i = 0; i < 4; ++i) {
            const int rl = wr * 64 + rt * 16 + quad * 4 + i;
            const int gr = row0 + rl;
            if (gr >= N) continue;
            const float sum = sStats[rl][0][0] + sStats[rl][1][0];
            const float sq  = sStats[rl][0][1] + sStats[rl][1][1];
            const float mu  = sum * (1.f / 256.f);
            const float var = sq * (1.f / 256.f) - mu * mu;
            const float rstd = 1.f / sqrtf(var + 1e-5f);
            const float rf = (float)gr;
            unsigned short* orow = hh + (size_t)gr * 256 + wc * 128 + l16;
#pragma unroll
            for (int ct = 0; ct < 8; ++ct) {
                const float v = fmaxf(acc[rt][ct][i] + bs[ct], 0.f);
                const float nrm = (v - mu) * rstd * gs[ct] + bv[ct];
                const float pe = cw_trig(rf * dv[ct], is_cos);
                orow[ct * 16] = f2h(nrm + pe);
            }
        }
    }
}

// Layer-1 GCN GEMM: A-resident chunk order, XCD-paired col tiles.
__global__ __launch_bounds__(256, 3)
void tg_gemm(const unsigned short* __restrict__ Ph,
             const unsigned short* __restrict__ Bt,
             const float* __restrict__ rowscale,
             unsigned short* __restrict__ out)
{
    __shared__ unsigned short sA[128 * 64], sB[128 * 64];  // 16 KB each

    const int t = threadIdx.x;
    const int w = t >> 6, lane = t & 63;
    const int quad = lane >> 4, l16 = lane & 15;
    const int wr = w >> 1, wc = w & 1;

    const int nwg = gridDim.x;
    const int swq = nwg >> 3, swr = nwg & 7;
    const int xcd = blockIdx.x & 7, oidx = blockIdx.x >> 3;
    const int lg = (xcd < swr ? xcd * (swq + 1)
                              : swr * (swq + 1) + (xcd - swr) * swq) + oidx;
    const int row0 = (lg >> 1) * 128;
    const int col0 = (lg & 1) * 128;

    floatx4 acc[4][4];
#pragma unroll
    for (int i = 0; i < 4; ++i)
#pragma unroll
        for (int j = 0; j < 4; ++j) acc[i][j] = (floatx4){0.f, 0.f, 0.f, 0.f};

    const int srow = lane >> 3;
    const int kgx  = (lane & 7) ^ srow;
    const int rsw  = l16 & 7;

    for (int c = 0; c < 8; ++c) {
        const int ka = (c >> 1) << 6;
        const int kb = ((c & 1) << 8) + ka;
        const bool stA = !(c & 1);
        if (c) __syncthreads();
#pragma unroll
        for (int i = 0; i < 4; ++i) {
            const int rr = w * 32 + i * 8;
            if (stA)
                gl_lds16(Ph + (size_t)(row0 + rr + srow) * 256 + ka + kgx * 8, &sA[rr * 64]);
            gl_lds16(Bt + (size_t)(col0 + rr + srow) * 512 + kb + kgx * 8, &sB[rr * 64]);
        }
        __syncthreads();
#pragma unroll
        for (int ks = 0; ks < 2; ++ks) {
            const int kq = ks * 4 + quad;
            half8 af[4], bfr[4];
#pragma unroll
            for (int rt = 0; rt < 4; ++rt) {
                const int r = wr * 64 + rt * 16 + l16;
                af[rt] = *(const half8*)&sA[r * 64 + ((kq ^ rsw) << 3)];
            }
#pragma unroll
            for (int ct = 0; ct < 4; ++ct) {
                const int n = wc * 64 + ct * 16 + l16;
                bfr[ct] = *(const half8*)&sB[n * 64 + ((kq ^ rsw) << 3)];
            }
#pragma unroll
            for (int ct = 0; ct < 4; ++ct)
#pragma unroll
                for (int rt = 0; rt < 4; ++rt)
                    acc[rt][ct] = __builtin_amdgcn_mfma_f32_16x16x32_f16(
                        af[rt], bfr[ct], acc[rt][ct], 0, 0, 0);
        }
    }

#pragma unroll
    for (int rt = 0; rt < 4; ++rt) {
#pragma unroll
        for (int i = 0; i < 4; ++i) {
            const int gr = row0 + wr * 64 + rt * 16 + quad * 4 + i;
            const float s = rowscale[gr];
#pragma unroll
            for (int ct = 0; ct < 4; ++ct) {
                const int gc = col0 + wc * 64 + ct * 16 + l16;
                out[(size_t)gr * 256 + gc] = f2h(acc[rt][ct][i] * s);
            }
        }
    }
}

// ---------------------------------------------------------------------------
// Fused aggregate_l + GEMM_{l+1}, BARRIER-FREE. 512 thr, 64 KB LDS,
// 2 blocks/CU, 16 waves/CU. Each wave owns 16 rows: gathers them into its
// private 8KB swizzled LDS strip (2 rows x 32 lanes per iter), fences with
// lgkmcnt(0), then GEMMs its 16x256 strip: A-frags from own LDS, B from
// global (L2-resident 512KB), acc[16], no __syncthreads anywhere.
// ---------------------------------------------------------------------------
__global__ __launch_bounds__(512, 4)
void tg_agg_gemm(const unsigned short* __restrict__ hwpIn,
                 const int* __restrict__ rowptr, const int* __restrict__ col,
                 const float* __restrict__ dinv, const float* __restrict__ bias,
                 const unsigned short* __restrict__ Bt,
                 unsigned short* __restrict__ hwpOut, int N)
{
    __shared__ unsigned short hA[8 * 16 * 256];   // 64 KB, 8 KB per wave

    const int t = threadIdx.x;
    const int w = t >> 6, lane = t & 63;
    const int row0 = blockIdx.x * 128 + w * 16;   // wave's 16 rows
    unsigned short* wA = hA + w * 4096;           // wave-private strip

    // ---- gather: 2 rows (32 lanes each) per iteration, 8 iterations ----
    {
        const int g2 = lane >> 5, hl = lane & 31;
        const int c = hl * 8;                     // 8 f16 = 16 B per lane
        const unsigned short* base = hwpIn + c;
        const float4 b0v = *(const float4*)&bias[c];
        const float4 b1v = *(const float4*)&bias[c + 4];
        for (int it = 0; it < 8; ++it) {
            const int lr = it * 2 + g2;
            const int row = row0 + lr;
            us8 o = {0, 0, 0, 0, 0, 0, 0, 0};
            if (row < N) {
                const int beg = rowptr[row], end = rowptr[row + 1];
                const us8 sv = *(const us8*)(base + (size_t)row * 256);
                float a[8];
#pragma unroll
                for (int j = 0; j < 8; ++j) a[j] = h2f(sv[j]);
                int p = beg;
                int rem = end - beg;
                int c0[8];
                if (rem >= 8) {
#pragma unroll
                    for (int u = 0; u < 8; ++u) c0[u] = col[p + u];
                }
                while (rem >= 8) {
                    int c1[8];
                    const bool more = rem >= 16;
                    if (more) {
#pragma unroll
                        for (int u = 0; u < 8; ++u) c1[u] = col[p + 8 + u];
                    }
                    us8 v[8];
#pragma unroll
                    for (int u = 0; u < 8; ++u)
                        v[u] = *(const us8*)(base + (size_t)c0[u] * 256);
#pragma unroll
                    for (int u = 0; u < 8; ++u)
#pragma unroll
                        for (int j = 0; j < 8; ++j) a[j] += h2f(v[u][j]);
                    if (more) {
#pragma unroll
                        for (int u = 0; u < 8; ++u) c0[u] = c1[u];
                    }
                    p += 8; rem -= 8;
                }
                if (rem > 0) {
                    const int last = end - 1;
                    int ci[8];
#pragma unroll
                    for (int u = 0; u < 8; ++u) {
                        const int pp = (p + u < last) ? p + u : last;
                        ci[u] = col[pp];
                    }
                    us8 v[8];
#pragma unroll
                    for (int u = 0; u < 8; ++u)
                        v[u] = *(const us8*)(base + (size_t)(u < rem ? ci[u] : row) * 256);
#pragma unroll
                    for (int u = 0; u < 8; ++u) {
                        if (u < rem) {
#pragma unroll
                            for (int j = 0; j < 8; ++j) a[j] += h2f(v[u][j]);
                        }
                    }
                }
                const float di = dinv[row];
                o[0] = f2h(fmaxf(di * a[0] + b0v.x, 0.f));
                o[1] = f2h(fmaxf(di * a[1] + b0v.y, 0.f));
                o[2] = f2h(fmaxf(di * a[2] + b0v.z, 0.f));
                o[3] = f2h(fmaxf(di * a[3] + b0v.w, 0.f));
                o[4] = f2h(fmaxf(di * a[4] + b1v.x, 0.f));
                o[5] = f2h(fmaxf(di * a[5] + b1v.y, 0.f));
                o[6] = f2h(fmaxf(di * a[6] + b1v.z, 0.f));
                o[7] = f2h(fmaxf(di * a[7] + b1v.w, 0.f));
            }
            // swizzled store: slot hl -> hl ^ (lr & 7)
            *(us8*)&wA[lr * 256 + ((hl ^ (lr & 7)) << 3)] = o;
        }
    }
    // wave-local LDS fence: cross-lane write->read, compiler can't see dep
    asm volatile("s_waitcnt lgkmcnt(0)" ::: "memory");
    __builtin_amdgcn_sched_barrier(0);

    // ---- GEMM: this wave's 16 rows x 256 cols, B from global (L2) ----
    const int quad = lane >> 4, l16 = lane & 15;
    const int r7 = l16 & 7;

    floatx4 acc[16];
#pragma unroll
    for (int i = 0; i < 16; ++i) acc[i] = (floatx4){0.f, 0.f, 0.f, 0.f};

    for (int ka4 = 0; ka4 < 4; ++ka4) {
        const int ka = ka4 * 64;
        // A-frags for ks=0/1, reused across Bh and Bl
        const half8 af0 = *(const half8*)
            &wA[l16 * 256 + (((ka >> 3) + (quad ^ r7)) << 3)];
        const half8 af1 = *(const half8*)
            &wA[l16 * 256 + (((ka >> 3) + ((quad + 4) ^ r7)) << 3)];
#pragma unroll
        for (int hf = 0; hf < 2; ++hf) {
            const int kb = hf * 256 + ka + quad * 8;
#pragma unroll
            for (int ct4 = 0; ct4 < 4; ++ct4) {
                half8 b0[4], b1[4];
#pragma unroll
                for (int j = 0; j < 4; ++j) {
                    const int n = (ct4 * 4 + j) * 16 + l16;
                    b0[j] = *(const half8*)&Bt[(size_t)n * 512 + kb];
                    b1[j] = *(const half8*)&Bt[(size_t)n * 512 + kb + 32];
                }
#pragma unroll
                for (int j = 0; j < 4; ++j) {
                    acc[ct4 * 4 + j] = __builtin_amdgcn_mfma_f32_16x16x32_f16(
                        af0, b0[j], acc[ct4 * 4 + j], 0, 0, 0);
                    acc[ct4 * 4 + j] = __builtin_amdgcn_mfma_f32_16x16x32_f16(
                        af1, b1[j], acc[ct4 * 4 + j], 0, 0, 0);
                }
            }
        }
    }

    // epilogue: hwpOut = f16(acc * dinv_row)
    float di[4];
#pragma unroll
    for (int i = 0; i < 4; ++i) di[i] = dinv[row0 + quad * 4 + i];
#pragma unroll
    for (int ct = 0; ct < 16; ++ct) {
#pragma unroll
        for (int i = 0; i < 4; ++i) {
            const int gr = row0 + quad * 4 + i;
            hwpOut[(size_t)gr * 256 + ct * 16 + l16] = f2h(acc[ct][i] * di[i]);
        }
    }
}

// count pass also records each edge's slot within its dst row (perm).
__global__ void tg_count(const int* __restrict__ dst, int* __restrict__ deg,
                         int* __restrict__ perm, int E)
{
    const int e = blockIdx.x * blockDim.x + threadIdx.x;
    if (e < E) perm[e] = atomicAdd(&deg[dst[e]], 1);
}

__global__ void tg_dinv(const int* __restrict__ deg, float* __restrict__ dinv, int N)
{
    const int i = blockIdx.x * blockDim.x + threadIdx.x;
    if (i < N) dinv[i] = 1.f / sqrtf((float)(deg[i] + 1));  // +1 self-loop
}

__global__ void tg_scan1(const int* __restrict__ cnt, int* __restrict__ out,
                         int* __restrict__ sums, int N)
{
    __shared__ int tmp[1024];
    const int t = threadIdx.x;
    const int gid = blockIdx.x * 1024 + t;
    const int v = (gid < N) ? cnt[gid] : 0;
    tmp[t] = v;
    __syncthreads();
    for (int o = 1; o < 1024; o <<= 1) {
        const int add = (t >= o) ? tmp[t - o] : 0;
        __syncthreads();
        tmp[t] += add;
        __syncthreads();
    }
    if (gid < N) out[gid] = tmp[t] - v;
    if (t == 1023) sums[blockIdx.x] = tmp[t];
}

__global__ void tg_scan2(int* __restrict__ sums, int nb)
{
    __shared__ int tmp[1024];
    const int t = threadIdx.x;
    const int v = (t < nb) ? sums[t] : 0;
    tmp[t] = v;
    __syncthreads();
    for (int o = 1; o < 1024; o <<= 1) {
        const int add = (t >= o) ? tmp[t - o] : 0;
        __syncthreads();
        tmp[t] += add;
        __syncthreads();
    }
    if (t < nb) sums[t] = tmp[t] - v;
}

__global__ void tg_scan3(int* __restrict__ rowptr, const int* __restrict__ offs,
                         int N, int E)
{
    const int gid = blockIdx.x * 1024 + threadIdx.x;
    if (gid < N) rowptr[gid] += offs[gid >> 10];
    else if (gid == N) rowptr[N] = E;
}

// atomic-free fill using perm from the count pass
__global__ void tg_fill(const int* __restrict__ src, const int* __restrict__ dst,
                        const int* __restrict__ rowptr, const int* __restrict__ perm,
                        int* __restrict__ col, int E)
{
    const int e = blockIdx.x * blockDim.x + threadIdx.x;
    if (e >= E) return;
    col[rowptr[dst[e]] + perm[e]] = src[e];
}

// Final standalone aggregate (layer 3 -> hh, consumed by pool).
__global__ void tg_aggregate_h(const unsigned short* __restrict__ hwpb,
                               const int* __restrict__ rowptr, const int* __restrict__ col,
                               const float* __restrict__ dinv, const float* __restrict__ bias,
                               unsigned short* __restrict__ hh, int N)
{
    const int gt = blockIdx.x * blockDim.x + threadIdx.x;
    const int row = gt >> 5;               // 32-thread group per row
    if (row >= N) return;
    const int hl = gt & 31;
    const int c = hl * 8;                  // 8 halves = 16 B per lane

    const unsigned short* base = hwpb + c;
    const int beg = rowptr[row], end = rowptr[row + 1];

    const us8 sv = *(const us8*)(base + (size_t)row * 256);
    float a[8];
#pragma unroll
    for (int j = 0; j < 8; ++j) a[j] = h2f(sv[j]);

    int p = beg;
    int rem = end - beg;
    int c0[8];
    if (rem >= 8) {
#pragma unroll
        for (int u = 0; u < 8; ++u) c0[u] = col[p + u];
    }
    while (rem >= 8) {
        int c1[8];
        const bool more = rem >= 16;
        if (more) {
#pragma unroll
            for (int u = 0; u < 8; ++u) c1[u] = col[p + 8 + u];
        }
        us8 v[8];
#pragma unroll
        for (int u = 0; u < 8; ++u)
            v[u] = *(const us8*)(base + (size_t)c0[u] * 256);
#pragma unroll
        for (int u = 0; u < 8; ++u)
#pragma unroll
            for (int j = 0; j < 8; ++j) a[j] += h2f(v[u][j]);
        if (more) {
#pragma unroll
            for (int u = 0; u < 8; ++u) c0[u] = c1[u];
        }
        p += 8; rem -= 8;
    }
    if (rem > 0) {
        const int last = end - 1;
        int ci[8];
#pragma unroll
        for (int u = 0; u < 8; ++u) {
            const int pp = (p + u < last) ? p + u : last;   // clamp: no OOB
            ci[u] = col[pp];
        }
        us8 v[8];
#pragma unroll
        for (int u = 0; u < 8; ++u)
            v[u] = *(const us8*)(base + (size_t)(u < rem ? ci[u] : row) * 256);
#pragma unroll
        for (int u = 0; u < 8; ++u) {
            if (u < rem) {
#pragma unroll
                for (int j = 0; j < 8; ++j) a[j] += h2f(v[u][j]);
            }
        }
    }

    const float di = dinv[row];
    const float4 b0 = *(const float4*)&bias[c];
    const float4 b1 = *(const float4*)&bias[c + 4];
    us8 o;
    o[0] = f2h(fmaxf(di * a[0] + b0.x, 0.f));
    o[1] = f2h(fmaxf(di * a[1] + b0.y, 0.f));
    o[2] = f2h(fmaxf(di * a[2] + b0.z, 0.f));
    o[3] = f2h(fmaxf(di * a[3] + b0.w, 0.f));
    o[4] = f2h(fmaxf(di * a[4] + b1.x, 0.f));
    o[5] = f2h(fmaxf(di * a[5] + b1.y, 0.f));
    o[6] = f2h(fmaxf(di * a[6] + b1.z, 0.f));
    o[7] = f2h(fmaxf(di * a[7] + b1.w, 0.f));
    *(us8*)&hh[(size_t)row * 256 + c] = o;
}

// Mean-pool: block per graph (ranges inlined via binary search on batch).
__global__ void tg_pool(const unsigned short* __restrict__ hh,
                        const int* __restrict__ batch, float* __restrict__ pooled,
                        int N, int G)
{
    __shared__ float sh[4][64][4];
    __shared__ int sBE[2];
    const int g = blockIdx.x;
    const int t = threadIdx.x;
    if (t < 2) {
        const int target = g + t;
        int lo = 0, hi = N;
        while (lo < hi) {
            const int mid = (lo + hi) >> 1;
            if (batch[mid] < target) lo = mid + 1; else hi = mid;
        }
        sBE[t] = lo;
    }
    __syncthreads();
    const int beg = sBE[0], end = sBE[1];
    const int wv = t >> 6, lane = t & 63;
    const int c = lane * 4;
    float s0 = 0.f, s1 = 0.f, s2 = 0.f, s3 = 0.f;
    for (int r = beg + wv; r < end; r += 4) {
        const ushort4 vh = *(const ushort4*)&hh[(size_t)r * 256 + c];
        s0 += h2f(vh.x); s1 += h2f(vh.y); s2 += h2f(vh.z); s3 += h2f(vh.w);
    }
    sh[wv][lane][0] = s0; sh[wv][lane][1] = s1;
    sh[wv][lane][2] = s2; sh[wv][lane][3] = s3;
    __syncthreads();
    if (t < 64) {
        const float inv = 1.f / fmaxf((float)(end - beg), 1.f);
        float4 o;
        o.x = (sh[0][t][0] + sh[1][t][0] + sh[2][t][0] + sh[3][t][0]) * inv;
        o.y = (sh[0][t][1] + sh[1][t][1] + sh[2][t][1] + sh[3][t][1]) * inv;
        o.z = (sh[0][t][2] + sh[1][t][2] + sh[2][t][2] + sh[3][t][2]) * inv;
        o.w = (sh[0][t][3] + sh[1][t][3] + sh[2][t][3] + sh[3][t][3]) * inv;
        *(float4*)&pooled[(size_t)g * 256 + t * 4] = o;
    }
}

// Fused 3-layer classifier MLP: one block per graph.
__global__ __launch_bounds__(256)
void tg_mlp3(const float* __restrict__ pooled,
             const float* __restrict__ W0, const float* __restrict__ b0,
             const float* __restrict__ W1, const float* __restrict__ b1,
             const float* __restrict__ W2, const float* __restrict__ b2,
             float* __restrict__ out, int H2, int Cc)
{
    __shared__ float zin[256];
    __shared__ float z0[256];
    __shared__ float z1[256];
    const int g = blockIdx.x;
    const int t = threadIdx.x;
    zin[t] = pooled[(size_t)g * 256 + t];
    __syncthreads();
    float a = 0.f;
    for (int k = 0; k < 256; ++k) a += zin[k] * W0[(size_t)k * 256 + t];
    z0[t] = fmaxf(a + b0[t], 0.f);
    __syncthreads();
    if (t < H2) {
        float a1 = 0.f;
        for (int k = 0; k < 256; ++k) a1 += z0[k] * W1[(size_t)k * H2 + t];
        z1[t] = fmaxf(a1 + b1[t], 0.f);
    }
    __syncthreads();
    if (t < Cc) {
        float a2 = 0.f;
        for (int k = 0; k < H2; ++k) a2 += z1[k] * W2[(size_t)k * Cc + t];
        out[(size_t)g * Cc + t] = a2 + b2[t];
    }
}

extern "C" void kernel_launch(void* const* d_in, const int* in_sizes, int n_in,
                              void* d_out, int out_size, void* d_ws, size_t ws_size,
                              hipStream_t stream)
{
    const float* x    = (const float*)d_in[0];
    const float* W_ft = (const float*)d_in[1];
    const float* b_ft = (const float*)d_in[2];
    const float* ln_g = (const float*)d_in[3];
    const float* ln_b = (const float*)d_in[4];
    const float* W_g[3] = {(const float*)d_in[5], (const float*)d_in[7], (const float*)d_in[9]};
    const float* b_g[3] = {(const float*)d_in[6], (const float*)d_in[8], (const float*)d_in[10]};
    const float* W_c0 = (const float*)d_in[11];
    const float* b_c0 = (const float*)d_in[12];
    const float* W_c1 = (const float*)d_in[13];
    const float* b_c1 = (const float*)d_in[14];
    const float* W_c2 = (const float*)d_in[15];
    const float* b_c2 = (const float*)d_in[16];
    const int*   edge  = (const int*)d_in[17];
    const int*   batch = (const int*)d_in[18];

    const int N    = in_sizes[18];        // 100000
    const int E    = in_sizes[17] / 2;    // 1600000
    const int Mpad = (N + 127) & ~127;    // 100096
    const int H2   = in_sizes[14];        // 128
    const int Cc   = in_sizes[15] / H2;   // 4
    const int G    = out_size / Cc;       // 512

    const int* srcI = edge;
    const int* dstI = edge + E;

    size_t off = 0;
    auto alloc = [&](size_t bytes) {
        char* p = (char*)d_ws + off;
        off = (off + bytes + 255) & ~(size_t)255;
        return p;
    };
    unsigned short* hh    = (unsigned short*)alloc((size_t)Mpad * 256 * 2);
    unsigned short* hwpbA = (unsigned short*)alloc((size_t)Mpad * 256 * 2);
    unsigned short* hwpbB = (unsigned short*)alloc((size_t)Mpad * 256 * 2);
    float* dinv   = (float*)alloc((size_t)Mpad * 4);
    int*   deg    = (int*)alloc((size_t)Mpad * 4);
    int*   rowptr = (int*)alloc((size_t)(N + 1) * 4);
    int*   perm   = (int*)alloc((size_t)E * 4);
    int*   col    = (int*)alloc((size_t)E * 4);
    int*   bsums  = (int*)alloc(1024 * 4);
    float* pooled = (float*)alloc((size_t)G * 256 * 4);
    unsigned short* Bt[4];
    for (int i = 0; i < 4; ++i)
        Bt[i] = (unsigned short*)alloc((size_t)256 * 512 * 2);
    (void)ws_size; (void)n_in;

    hipMemsetAsync(deg, 0, (size_t)Mpad * 4, stream);
    // zero pad rows of h plane (read by layer-1 GEMM A staging)
    hipMemsetAsync(hh + (size_t)N * 256, 0, (size_t)(Mpad - N) * 256 * 2, stream);

    // 0. weight prep
    tg_splitB<<<dim3(4, 4, 4), dim3(256), 0, stream>>>(
        W_ft, W_g[0], W_g[1], W_g[2], Bt[0], Bt[1], Bt[2], Bt[3]);

    // 1. fused feature transform + LayerNorm + PE -> single f16 h plane
    tg_ft_ln<<<dim3(Mpad / 128), dim3(256), 0, stream>>>(
        x, Bt[0], b_ft, ln_g, ln_b, hh, N);

    // 2. degrees + CSR build (rows = dst, cols = src)
    tg_count<<<dim3((E + 255) / 256), dim3(256), 0, stream>>>(dstI, deg, perm, E);
    tg_dinv<<<dim3((Mpad + 255) / 256), dim3(256), 0, stream>>>(deg, dinv, Mpad);
    const int NB = (N + 1023) / 1024;
    tg_scan1<<<dim3(NB), dim3(1024), 0, stream>>>(deg, rowptr, bsums, N);
    tg_scan2<<<dim3(1), dim3(1024), 0, stream>>>(bsums, NB);
    tg_scan3<<<dim3((N + 1024) / 1024), dim3(1024), 0, stream>>>(rowptr, bsums, N, E);
    tg_fill<<<dim3((E + 255) / 256), dim3(256), 0, stream>>>(srcI, dstI, rowptr, perm, col, E);

    // 3. GCN layers: gemm1 standalone; layers 2,3 fused (agg_l + gemm_{l+1});
    //    final aggregate standalone -> hh
    const int nbx = (Mpad / 128) * 2;
    tg_gemm<<<dim3(nbx), dim3(256), 0, stream>>>(hh, Bt[1], dinv, hwpbA);
    const int nfb = Mpad / 128;
    tg_agg_gemm<<<dim3(nfb), dim3(512), 0, stream>>>(hwpbA, rowptr, col, dinv,
                                                     b_g[0], Bt[2], hwpbB, N);
    tg_agg_gemm<<<dim3(nfb), dim3(512), 0, stream>>>(hwpbB, rowptr, col, dinv,
                                                     b_g[1], Bt[3], hwpbA, N);
    tg_aggregate_h<<<dim3((N + 7) / 8), dim3(256), 0, stream>>>(hwpbA, rowptr, col, dinv,
                                                                b_g[2], hh, N);

    // 4. per-graph mean pool (ranges inlined)
    tg_pool<<<dim3(G), dim3(256), 0, stream>>>(hh, batch, pooled, N, G);

    // 5. fused classifier MLP
    tg_mlp3<<<dim3(G), dim3(256), 0, stream>>>(pooled, W_c0, b_c0, W_c1, b_c1,
                                               W_c2, b_c2, (float*)d_out, H2, Cc);
}

// Round 6
// 940.129 us; speedup vs baseline: 1.3694x; 1.3694x over previous
//
#include <hip/hip_runtime.h>
#include <math.h>

// ---------------------------------------------------------------------------
// Temporal GNN. Round 13:
//  * tg_agg_gemm: revert to r11's LDS-staged-B structure (r12's B-from-
//    global thrashed L1 and stole the gather's per-CU VMEM concurrency ->
//    1.5 TB/s). New geometry: 64-row tiles, 256 threads, 48 KB LDS ->
//    3 blocks/CU. Gather runs at 12 waves/CU (the occupancy that measured
//    3.85 TB/s standalone); 3 independent small blocks per CU mix phases
//    stochastically so the barrier-paced GEMM hides under other blocks'
//    gathers. Accumulation order identical to r11.
//  * Everything else = round 11.
// ---------------------------------------------------------------------------

typedef __attribute__((ext_vector_type(8))) _Float16 half8;  // MFMA A/B frag
typedef __attribute__((ext_vector_type(4))) float floatx4;   // MFMA C/D
typedef __attribute__((ext_vector_type(8))) unsigned short us8; // 16B f16 vec

union HU { _Float16 h; unsigned short u; };

static __device__ __forceinline__ unsigned short f2h(float f) {
    HU x; x.h = (_Float16)f; return x.u;          // v_cvt_f16_f32 (RNE)
}
static __device__ __forceinline__ float h2f(unsigned short s) {
    HU x; x.u = s; return (float)x.h;
}

// async 16B/lane global -> LDS (dest = wave-uniform base + lane*16)
static __device__ __forceinline__ void gl_lds16(const void* g, void* l) {
    __builtin_amdgcn_global_load_lds(
        (const __attribute__((address_space(1))) unsigned int*)(g),
        (__attribute__((address_space(3))) unsigned int*)(l), 16, 0, 0);
}

// sin/cos(ang) for ang up to ~1e5 rad: Cody-Waite 3-term reduction
// + hardware trig on revolutions.
static __device__ __forceinline__ float cw_trig(float ang, bool is_cos) {
    const float i2pi = 0.15915494309189535f;
    const float k = rintf(ang * i2pi);
    float r = fmaf(k, -6.28125f, ang);
    r = fmaf(k, -1.9352436065673828e-3f, r);
    r = fmaf(k, -6.3573019e-8f, r);
    const float rv = r * i2pi;
    return is_cos ? __builtin_amdgcn_cosf(rv) : __builtin_amdgcn_sinf(rv);
}

// Split W[256][256] (k-major) into Bt'[n][512] = [Bh | Bl] f16 (transposed).
__global__ void tg_splitB(const float* __restrict__ W0, const float* __restrict__ W1,
                          const float* __restrict__ W2, const float* __restrict__ W3,
                          unsigned short* __restrict__ B0, unsigned short* __restrict__ B1,
                          unsigned short* __restrict__ B2, unsigned short* __restrict__ B3)
{
    const float* Ws[4] = {W0, W1, W2, W3};
    unsigned short* Bs[4] = {B0, B1, B2, B3};
    const float* W = Ws[blockIdx.z];
    unsigned short* Bt = Bs[blockIdx.z];

    __shared__ float T[64][68];
    const int tk = blockIdx.x * 64, tn = blockIdx.y * 64;
    const int t = threadIdx.x;
#pragma unroll
    for (int j = 0; j < 4; ++j) {
        const int idx = t + 256 * j;
        const int k = idx >> 4, c4 = (idx & 15) * 4;
        const float4 v = *(const float4*)&W[(size_t)(tk + k) * 256 + tn + c4];
        T[k][c4] = v.x; T[k][c4 + 1] = v.y; T[k][c4 + 2] = v.z; T[k][c4 + 3] = v.w;
    }
    __syncthreads();
#pragma unroll
    for (int j = 0; j < 4; ++j) {
        const int idx = t + 256 * j;
        const int n = idx >> 4, q = (idx & 15) * 4;
        unsigned short hh[4], ll[4];
#pragma unroll
        for (int i = 0; i < 4; ++i) {
            const float f = T[q + i][n];
            hh[i] = f2h(f);
            ll[i] = f2h(f - h2f(hh[i]));
        }
        uint2 hp, lp;
        hp.x = (unsigned)hh[0] | ((unsigned)hh[1] << 16);
        hp.y = (unsigned)hh[2] | ((unsigned)hh[3] << 16);
        lp.x = (unsigned)ll[0] | ((unsigned)ll[1] << 16);
        lp.y = (unsigned)ll[2] | ((unsigned)ll[3] << 16);
        unsigned short* row = Bt + (size_t)(tn + n) * 512;
        *(uint2*)&row[tk + q]       = hp;   // Bh
        *(uint2*)&row[256 + tk + q] = lp;   // Bl
    }
}

// ---------------------------------------------------------------------------
// Fused FT GEMM + LayerNorm + PE (round-10 structure, unchanged).
// ---------------------------------------------------------------------------
__global__ __launch_bounds__(256, 2)
void tg_ft_ln(const float* __restrict__ x, const unsigned short* __restrict__ Bt,
              const float* __restrict__ bias, const float* __restrict__ lng,
              const float* __restrict__ lnb, unsigned short* __restrict__ hh, int N)
{
    __shared__ unsigned short sAh[128 * 64];   // 16 KB
    __shared__ unsigned short sAl[128 * 64];   // 16 KB
    __shared__ unsigned short sB[256 * 64];    // 32 KB (Bh then Bl)
    __shared__ float sStats[128][2][2];        // [row][wc][{sum,sumsq}] 2 KB
    __shared__ float sDiv[128];                // PE div table (512 B)

    const int t = threadIdx.x;
    const int w = t >> 6, lane = t & 63;
    const int quad = lane >> 4, l16 = lane & 15;
    const int wr = w >> 1, wc = w & 1;
    const int row0 = blockIdx.x * 128;

    if (t < 128) sDiv[t] = expf((float)(2 * t) * -0.035977892078031970f);

    floatx4 acc[4][8];
#pragma unroll
    for (int i = 0; i < 4; ++i)
#pragma unroll
        for (int j = 0; j < 8; ++j) acc[i][j] = (floatx4){0.f, 0.f, 0.f, 0.f};

    const int arow = t >> 1;
    const int ahalf = t & 1;
    const int srow = lane >> 3;
    const int kgx  = (lane & 7) ^ srow;
    const int rsw  = l16 & 7;

    for (int k4 = 0; k4 < 4; ++k4) {
        const int ka = k4 * 64;
        if (k4) __syncthreads();
        // issue sB = Bh(ka) first (async, overlaps the A chain)
#pragma unroll
        for (int i = 0; i < 8; ++i) {
            const int rr = w * 64 + i * 8;
            gl_lds16(Bt + (size_t)(rr + srow) * 512 + ka + kgx * 8, &sB[rr * 64]);
        }
        // stage A: read f32 x, split to hi/lo f16, swizzled ds_write
        {
            const int grow = row0 + arow;
            const bool ok = grow < N;
            const float* xp = x + (size_t)grow * 256 + ka + ahalf * 32;
#pragma unroll
            for (int j = 0; j < 4; ++j) {
                const int kg = ahalf * 4 + j;
                float4 v0 = {0.f, 0.f, 0.f, 0.f}, v1 = {0.f, 0.f, 0.f, 0.f};
                if (ok) {
                    v0 = *(const float4*)(xp + j * 8);
                    v1 = *(const float4*)(xp + j * 8 + 4);
                }
                const float f[8] = {v0.x, v0.y, v0.z, v0.w, v1.x, v1.y, v1.z, v1.w};
                us8 hi, lo;
#pragma unroll
                for (int i = 0; i < 8; ++i) {
                    hi[i] = f2h(f[i]);
                    lo[i] = f2h(f[i] - h2f(hi[i]));
                }
                const int ad = arow * 64 + ((kg ^ (arow & 7)) << 3);
                *(us8*)&sAh[ad] = hi;
                *(us8*)&sAl[ad] = lo;
            }
        }
        __syncthreads();
        // P0 + P1: Ah.Bh + Al.Bh
#pragma unroll
        for (int ks = 0; ks < 2; ++ks) {
            const int kq = ks * 4 + quad;
            half8 afh[4], afl[4];
#pragma unroll
            for (int rt = 0; rt < 4; ++rt) {
                const int r = wr * 64 + rt * 16 + l16;
                const int off = r * 64 + ((kq ^ rsw) << 3);
                afh[rt] = *(const half8*)&sAh[off];
                afl[rt] = *(const half8*)&sAl[off];
            }
#pragma unroll
            for (int cb = 0; cb < 2; ++cb) {
                half8 bfr[4];
#pragma unroll
                for (int c4 = 0; c4 < 4; ++c4) {
                    const int n = wc * 128 + (cb * 4 + c4) * 16 + l16;
                    bfr[c4] = *(const half8*)&sB[n * 64 + ((kq ^ rsw) << 3)];
                }
#pragma unroll
                for (int c4 = 0; c4 < 4; ++c4)
#pragma unroll
                    for (int rt = 0; rt < 4; ++rt) {
                        acc[rt][cb * 4 + c4] = __builtin_amdgcn_mfma_f32_16x16x32_f16(
                            afh[rt], bfr[c4], acc[rt][cb * 4 + c4], 0, 0, 0);
                        acc[rt][cb * 4 + c4] = __builtin_amdgcn_mfma_f32_16x16x32_f16(
                            afl[rt], bfr[c4], acc[rt][cb * 4 + c4], 0, 0, 0);
                    }
            }
        }
        __syncthreads();
        // stage sB = Bl(ka)
#pragma unroll
        for (int i = 0; i < 8; ++i) {
            const int rr = w * 64 + i * 8;
            gl_lds16(Bt + (size_t)(rr + srow) * 512 + 256 + ka + kgx * 8, &sB[rr * 64]);
        }
        __syncthreads();
        // P2: Ah.Bl
#pragma unroll
        for (int ks = 0; ks < 2; ++ks) {
            const int kq = ks * 4 + quad;
            half8 afh[4];
#pragma unroll
            for (int rt = 0; rt < 4; ++rt) {
                const int r = wr * 64 + rt * 16 + l16;
                afh[rt] = *(const half8*)&sAh[r * 64 + ((kq ^ rsw) << 3)];
            }
#pragma unroll
            for (int cb = 0; cb < 2; ++cb) {
                half8 bfr[4];
#pragma unroll
                for (int c4 = 0; c4 < 4; ++c4) {
                    const int n = wc * 128 + (cb * 4 + c4) * 16 + l16;
                    bfr[c4] = *(const half8*)&sB[n * 64 + ((kq ^ rsw) << 3)];
                }
#pragma unroll
                for (int c4 = 0; c4 < 4; ++c4)
#pragma unroll
                    for (int rt = 0; rt < 4; ++rt)
                        acc[rt][cb * 4 + c4] = __builtin_amdgcn_mfma_f32_16x16x32_f16(
                            afh[rt], bfr[c4], acc[rt][cb * 4 + c4], 0, 0, 0);
            }
        }
    }

    float bs[8], gs[8], bv[8], dv[8];
#pragma unroll
    for (int ct = 0; ct < 8; ++ct) {
        const int gc = wc * 128 + ct * 16 + l16;
        bs[ct] = bias[gc]; gs[ct] = lng[gc]; bv[ct] = lnb[gc];
        dv[ct] = sDiv[gc >> 1];
    }

#pragma unroll
    for (int rt = 0; rt < 4; ++rt) {
#pragma unroll
        for (int i = 0; i < 4; ++i) {
            float s = 0.f, q = 0.f;
#pragma unroll
            for (int ct = 0; ct < 8; ++ct) {
                const float v = fmaxf(acc[rt][ct][i] + bs[ct], 0.f);
                s += v; q += v * v;
            }
#pragma unroll
            for (int m = 1; m < 16; m <<= 1) {
                s += __shfl_xor(s, m, 64);
                q += __shfl_xor(q, m, 64);
            }
            if (l16 == 0) {
                const int rl = wr * 64 + rt * 16 + quad * 4 + i;
                sStats[rl][wc][0] = s;
                sStats[rl][wc][1] = q;
            }
        }
    }
    __syncthreads();

    const bool is_cos = (l16 & 1);
#pragma unroll
    for (int rt = 0; rt < 4; ++rt) {
#pragma unroll
        for (int i = 0; i < 4; ++i) {
            const int rl = wr * 64 + rt * 16 + quad * 4 + i;
            const int gr = row0 + rl;
            if (gr >= N) continue;
            const float sum = sStats[rl][0][0] + sStats[rl][1][0];
            const float sq  = sStats[rl][0][1] + sStats[rl][1][1];
            const float mu  = sum * (1.f / 256.f);
            const float var = sq * (1.f / 256.f) - mu * mu;
            const float rstd = 1.f / sqrtf(var + 1e-5f);
            const float rf = (float)gr;
            unsigned short* orow = hh + (size_t)gr * 256 + wc * 128 + l16;
#pragma unroll
            for (int ct = 0; ct < 8; ++ct) {
                const float v = fmaxf(acc[rt][ct][i] + bs[ct], 0.f);
                const float nrm = (v - mu) * rstd * gs[ct] + bv[ct];
                const float pe = cw_trig(rf * dv[ct], is_cos);
                orow[ct * 16] = f2h(nrm + pe);
            }
        }
    }
}

// Layer-1 GCN GEMM: A-resident chunk order, XCD-paired col tiles.
__global__ __launch_bounds__(256, 3)
void tg_gemm(const unsigned short* __restrict__ Ph,
             const unsigned short* __restrict__ Bt,
             const float* __restrict__ rowscale,
             unsigned short* __restrict__ out)
{
    __shared__ unsigned short sA[128 * 64], sB[128 * 64];  // 16 KB each

    const int t = threadIdx.x;
    const int w = t >> 6, lane = t & 63;
    const int quad = lane >> 4, l16 = lane & 15;
    const int wr = w >> 1, wc = w & 1;

    const int nwg = gridDim.x;
    const int swq = nwg >> 3, swr = nwg & 7;
    const int xcd = blockIdx.x & 7, oidx = blockIdx.x >> 3;
    const int lg = (xcd < swr ? xcd * (swq + 1)
                              : swr * (swq + 1) + (xcd - swr) * swq) + oidx;
    const int row0 = (lg >> 1) * 128;
    const int col0 = (lg & 1) * 128;

    floatx4 acc[4][4];
#pragma unroll
    for (int i = 0; i < 4; ++i)
#pragma unroll
        for (int j = 0; j < 4; ++j) acc[i][j] = (floatx4){0.f, 0.f, 0.f, 0.f};

    const int srow = lane >> 3;
    const int kgx  = (lane & 7) ^ srow;
    const int rsw  = l16 & 7;

    for (int c = 0; c < 8; ++c) {
        const int ka = (c >> 1) << 6;
        const int kb = ((c & 1) << 8) + ka;
        const bool stA = !(c & 1);
        if (c) __syncthreads();
#pragma unroll
        for (int i = 0; i < 4; ++i) {
            const int rr = w * 32 + i * 8;
            if (stA)
                gl_lds16(Ph + (size_t)(row0 + rr + srow) * 256 + ka + kgx * 8, &sA[rr * 64]);
            gl_lds16(Bt + (size_t)(col0 + rr + srow) * 512 + kb + kgx * 8, &sB[rr * 64]);
        }
        __syncthreads();
#pragma unroll
        for (int ks = 0; ks < 2; ++ks) {
            const int kq = ks * 4 + quad;
            half8 af[4], bfr[4];
#pragma unroll
            for (int rt = 0; rt < 4; ++rt) {
                const int r = wr * 64 + rt * 16 + l16;
                af[rt] = *(const half8*)&sA[r * 64 + ((kq ^ rsw) << 3)];
            }
#pragma unroll
            for (int ct = 0; ct < 4; ++ct) {
                const int n = wc * 64 + ct * 16 + l16;
                bfr[ct] = *(const half8*)&sB[n * 64 + ((kq ^ rsw) << 3)];
            }
#pragma unroll
            for (int ct = 0; ct < 4; ++ct)
#pragma unroll
                for (int rt = 0; rt < 4; ++rt)
                    acc[rt][ct] = __builtin_amdgcn_mfma_f32_16x16x32_f16(
                        af[rt], bfr[ct], acc[rt][ct], 0, 0, 0);
        }
    }

#pragma unroll
    for (int rt = 0; rt < 4; ++rt) {
#pragma unroll
        for (int i = 0; i < 4; ++i) {
            const int gr = row0 + wr * 64 + rt * 16 + quad * 4 + i;
            const float s = rowscale[gr];
#pragma unroll
            for (int ct = 0; ct < 4; ++ct) {
                const int gc = col0 + wc * 64 + ct * 16 + l16;
                out[(size_t)gr * 256 + gc] = f2h(acc[rt][ct][i] * s);
            }
        }
    }
}

// ---------------------------------------------------------------------------
// Fused aggregate_l + GEMM_{l+1}. 64-row tile, 256 threads (4 waves),
// 48 KB LDS -> 3 blocks/CU (12 gather-waves/CU = standalone-aggregate
// occupancy). Phase 1: wave w gathers rows w*16..+15 (2 rows x 32 lanes
// per iter) into swizzled hA. Phase 2: GEMM hA[64x256] @ Bt (K'=512);
// sB staged 16 KB per (ka, Bh/Bl, col-half); wave w owns rows w*16..+15.
// Accumulation order identical to rounds 10-11.
// ---------------------------------------------------------------------------
__global__ __launch_bounds__(256, 3)
void tg_agg_gemm(const unsigned short* __restrict__ hwpIn,
                 const int* __restrict__ rowptr, const int* __restrict__ col,
                 const float* __restrict__ dinv, const float* __restrict__ bias,
                 const unsigned short* __restrict__ Bt,
                 unsigned short* __restrict__ hwpOut, int N)
{
    __shared__ unsigned short hA[64 * 256];   // 32 KB swizzled h tile
    __shared__ unsigned short sB[128 * 64];   // 16 KB

    const int t = threadIdx.x;
    const int w = t >> 6, lane = t & 63;
    const int row0 = blockIdx.x * 64;

    // ---- phase 1: gather 64 rows (wave w: rows w*16 .. w*16+15) ----
    {
        const int g2 = lane >> 5, hl = lane & 31;
        const int c = hl * 8;                 // 8 f16 = 16 B per lane
        const unsigned short* base = hwpIn + c;
        const float4 b0v = *(const float4*)&bias[c];
        const float4 b1v = *(const float4*)&bias[c + 4];
        for (int it = 0; it < 8; ++it) {
            const int lr = w * 16 + it * 2 + g2;
            const int row = row0 + lr;
            us8 o = {0, 0, 0, 0, 0, 0, 0, 0};
            if (row < N) {
                const int beg = rowptr[row], end = rowptr[row + 1];
                const us8 sv = *(const us8*)(base + (size_t)row * 256);
                float a[8];
#pragma unroll
                for (int j = 0; j < 8; ++j) a[j] = h2f(sv[j]);
                int p = beg;
                int rem = end - beg;
                int c0[8];
                if (rem >= 8) {
#pragma unroll
                    for (int u = 0; u < 8; ++u) c0[u] = col[p + u];
                }
                while (rem >= 8) {
                    int c1[8];
                    const bool more = rem >= 16;
                    if (more) {
#pragma unroll
                        for (int u = 0; u < 8; ++u) c1[u] = col[p + 8 + u];
                    }
                    us8 v[8];
#pragma unroll
                    for (int u = 0; u < 8; ++u)
                        v[u] = *(const us8*)(base + (size_t)c0[u] * 256);
#pragma unroll
                    for (int u = 0; u < 8; ++u)
#pragma unroll
                        for (int j = 0; j < 8; ++j) a[j] += h2f(v[u][j]);
                    if (more) {
#pragma unroll
                        for (int u = 0; u < 8; ++u) c0[u] = c1[u];
                    }
                    p += 8; rem -= 8;
                }
                if (rem > 0) {
                    const int last = end - 1;
                    int ci[8];
#pragma unroll
                    for (int u = 0; u < 8; ++u) {
                        const int pp = (p + u < last) ? p + u : last;
                        ci[u] = col[pp];
                    }
                    us8 v[8];
#pragma unroll
                    for (int u = 0; u < 8; ++u)
                        v[u] = *(const us8*)(base + (size_t)(u < rem ? ci[u] : row) * 256);
#pragma unroll
                    for (int u = 0; u < 8; ++u) {
                        if (u < rem) {
#pragma unroll
                            for (int j = 0; j < 8; ++j) a[j] += h2f(v[u][j]);
                        }
                    }
                }
                const float di = dinv[row];
                o[0] = f2h(fmaxf(di * a[0] + b0v.x, 0.f));
                o[1] = f2h(fmaxf(di * a[1] + b0v.y, 0.f));
                o[2] = f2h(fmaxf(di * a[2] + b0v.z, 0.f));
                o[3] = f2h(fmaxf(di * a[3] + b0v.w, 0.f));
                o[4] = f2h(fmaxf(di * a[4] + b1v.x, 0.f));
                o[5] = f2h(fmaxf(di * a[5] + b1v.y, 0.f));
                o[6] = f2h(fmaxf(di * a[6] + b1v.z, 0.f));
                o[7] = f2h(fmaxf(di * a[7] + b1v.w, 0.f));
            }
            // swizzled store: slot (hl&7) of chunk (c&~63) -> ^(lr&7)
            const int ad = lr * 256 + (c & ~63) + (((hl & 7) ^ (lr & 7)) << 3);
            *(us8*)&hA[ad] = o;
        }
    }
    __syncthreads();

    // ---- phase 2: GEMM hA[64x256] @ Bt -> hwpOut rows row0..+63 ----
    const int quad = lane >> 4, l16 = lane & 15;
    const int rsw = l16 & 7;
    const int srow = lane >> 3;
    const int kgx  = (lane & 7) ^ srow;
    const int r0 = w * 16;                 // wave's local row base

    floatx4 acc[2][8];                     // [col-half][col-tile]
#pragma unroll
    for (int i = 0; i < 2; ++i)
#pragma unroll
        for (int j = 0; j < 8; ++j) acc[i][j] = (floatx4){0.f, 0.f, 0.f, 0.f};

    for (int c8 = 0; c8 < 8; ++c8) {
        const int ka = (c8 >> 1) << 6;
        const int kb = ((c8 & 1) << 8) + ka;
#pragma unroll
        for (int ch = 0; ch < 2; ++ch) {
            if (c8 || ch) __syncthreads();     // prior MFMA done reading sB
            // stage sB = Bt rows [ch*128 .. +128) at k-offset kb (16 KB)
#pragma unroll
            for (int i = 0; i < 4; ++i) {
                const int rr = w * 32 + i * 8;
                gl_lds16(Bt + (size_t)(ch * 128 + rr + srow) * 512 + kb + kgx * 8,
                         &sB[rr * 64]);
            }
            __syncthreads();
#pragma unroll
            for (int ks = 0; ks < 2; ++ks) {
                const int kq = ks * 4 + quad;
                const half8 af = *(const half8*)
                    &hA[(r0 + l16) * 256 + ka + ((kq ^ rsw) << 3)];
                half8 bf[8];
#pragma unroll
                for (int ct = 0; ct < 8; ++ct) {
                    const int n = ct * 16 + l16;
                    bf[ct] = *(const half8*)&sB[n * 64 + ((kq ^ rsw) << 3)];
                }
#pragma unroll
                for (int ct = 0; ct < 8; ++ct)
                    acc[ch][ct] = __builtin_amdgcn_mfma_f32_16x16x32_f16(
                        af, bf[ct], acc[ch][ct], 0, 0, 0);
            }
        }
    }

    // epilogue: hwpOut = f16(acc * dinv_row)
    float di[4];
#pragma unroll
    for (int i = 0; i < 4; ++i) di[i] = dinv[row0 + r0 + quad * 4 + i];
#pragma unroll
    for (int ch = 0; ch < 2; ++ch) {
#pragma unroll
        for (int ct = 0; ct < 8; ++ct) {
#pragma unroll
            for (int i = 0; i < 4; ++i) {
                const int gr = row0 + r0 + quad * 4 + i;
                const int gc = ch * 128 + ct * 16 + l16;
                hwpOut[(size_t)gr * 256 + gc] = f2h(acc[ch][ct][i] * di[i]);
            }
        }
    }
}

// count pass also records each edge's slot within its dst row (perm).
__global__ void tg_count(const int* __restrict__ dst, int* __restrict__ deg,
                         int* __restrict__ perm, int E)
{
    const int e = blockIdx.x * blockDim.x + threadIdx.x;
    if (e < E) perm[e] = atomicAdd(&deg[dst[e]], 1);
}

__global__ void tg_dinv(const int* __restrict__ deg, float* __restrict__ dinv, int N)
{
    const int i = blockIdx.x * blockDim.x + threadIdx.x;
    if (i < N) dinv[i] = 1.f / sqrtf((float)(deg[i] + 1));  // +1 self-loop
}

__global__ void tg_scan1(const int* __restrict__ cnt, int* __restrict__ out,
                         int* __restrict__ sums, int N)
{
    __shared__ int tmp[1024];
    const int t = threadIdx.x;
    const int gid = blockIdx.x * 1024 + t;
    const int v = (gid < N) ? cnt[gid] : 0;
    tmp[t] = v;
    __syncthreads();
    for (int o = 1; o < 1024; o <<= 1) {
        const int add = (t >= o) ? tmp[t - o] : 0;
        __syncthreads();
        tmp[t] += add;
        __syncthreads();
    }
    if (gid < N) out[gid] = tmp[t] - v;
    if (t == 1023) sums[blockIdx.x] = tmp[t];
}

__global__ void tg_scan2(int* __restrict__ sums, int nb)
{
    __shared__ int tmp[1024];
    const int t = threadIdx.x;
    const int v = (t < nb) ? sums[t] : 0;
    tmp[t] = v;
    __syncthreads();
    for (int o = 1; o < 1024; o <<= 1) {
        const int add = (t >= o) ? tmp[t - o] : 0;
        __syncthreads();
        tmp[t] += add;
        __syncthreads();
    }
    if (t < nb) sums[t] = tmp[t] - v;
}

__global__ void tg_scan3(int* __restrict__ rowptr, const int* __restrict__ offs,
                         int N, int E)
{
    const int gid = blockIdx.x * 1024 + threadIdx.x;
    if (gid < N) rowptr[gid] += offs[gid >> 10];
    else if (gid == N) rowptr[N] = E;
}

// atomic-free fill using perm from the count pass
__global__ void tg_fill(const int* __restrict__ src, const int* __restrict__ dst,
                        const int* __restrict__ rowptr, const int* __restrict__ perm,
                        int* __restrict__ col, int E)
{
    const int e = blockIdx.x * blockDim.x + threadIdx.x;
    if (e >= E) return;
    col[rowptr[dst[e]] + perm[e]] = src[e];
}

// Final standalone aggregate (layer 3 -> hh, consumed by pool).
__global__ void tg_aggregate_h(const unsigned short* __restrict__ hwpb,
                               const int* __restrict__ rowptr, const int* __restrict__ col,
                               const float* __restrict__ dinv, const float* __restrict__ bias,
                               unsigned short* __restrict__ hh, int N)
{
    const int gt = blockIdx.x * blockDim.x + threadIdx.x;
    const int row = gt >> 5;               // 32-thread group per row
    if (row >= N) return;
    const int hl = gt & 31;
    const int c = hl * 8;                  // 8 halves = 16 B per lane

    const unsigned short* base = hwpb + c;
    const int beg = rowptr[row], end = rowptr[row + 1];

    const us8 sv = *(const us8*)(base + (size_t)row * 256);
    float a[8];
#pragma unroll
    for (int j = 0; j < 8; ++j) a[j] = h2f(sv[j]);

    int p = beg;
    int rem = end - beg;
    int c0[8];
    if (rem >= 8) {
#pragma unroll
        for (int u = 0; u < 8; ++u) c0[u] = col[p + u];
    }
    while (rem >= 8) {
        int c1[8];
        const bool more = rem >= 16;
        if (more) {
#pragma unroll
            for (int u = 0; u < 8; ++u) c1[u] = col[p + 8 + u];
        }
        us8 v[8];
#pragma unroll
        for (int u = 0; u < 8; ++u)
            v[u] = *(const us8*)(base + (size_t)c0[u] * 256);
#pragma unroll
        for (int u = 0; u < 8; ++u)
#pragma unroll
            for (int j = 0; j < 8; ++j) a[j] += h2f(v[u][j]);
        if (more) {
#pragma unroll
            for (int u = 0; u < 8; ++u) c0[u] = c1[u];
        }
        p += 8; rem -= 8;
    }
    if (rem > 0) {
        const int last = end - 1;
        int ci[8];
#pragma unroll
        for (int u = 0; u < 8; ++u) {
            const int pp = (p + u < last) ? p + u : last;   // clamp: no OOB
            ci[u] = col[pp];
        }
        us8 v[8];
#pragma unroll
        for (int u = 0; u < 8; ++u)
            v[u] = *(const us8*)(base + (size_t)(u < rem ? ci[u] : row) * 256);
#pragma unroll
        for (int u = 0; u < 8; ++u) {
            if (u < rem) {
#pragma unroll
                for (int j = 0; j < 8; ++j) a[j] += h2f(v[u][j]);
            }
        }
    }

    const float di = dinv[row];
    const float4 b0 = *(const float4*)&bias[c];
    const float4 b1 = *(const float4*)&bias[c + 4];
    us8 o;
    o[0] = f2h(fmaxf(di * a[0] + b0.x, 0.f));
    o[1] = f2h(fmaxf(di * a[1] + b0.y, 0.f));
    o[2] = f2h(fmaxf(di * a[2] + b0.z, 0.f));
    o[3] = f2h(fmaxf(di * a[3] + b0.w, 0.f));
    o[4] = f2h(fmaxf(di * a[4] + b1.x, 0.f));
    o[5] = f2h(fmaxf(di * a[5] + b1.y, 0.f));
    o[6] = f2h(fmaxf(di * a[6] + b1.z, 0.f));
    o[7] = f2h(fmaxf(di * a[7] + b1.w, 0.f));
    *(us8*)&hh[(size_t)row * 256 + c] = o;
}

// Mean-pool: block per graph (ranges inlined via binary search on batch).
__global__ void tg_pool(const unsigned short* __restrict__ hh,
                        const int* __restrict__ batch, float* __restrict__ pooled,
                        int N, int G)
{
    __shared__ float sh[4][64][4];
    __shared__ int sBE[2];
    const int g = blockIdx.x;
    const int t = threadIdx.x;
    if (t < 2) {
        const int target = g + t;
        int lo = 0, hi = N;
        while (lo < hi) {
            const int mid = (lo + hi) >> 1;
            if (batch[mid] < target) lo = mid + 1; else hi = mid;
        }
        sBE[t] = lo;
    }
    __syncthreads();
    const int beg = sBE[0], end = sBE[1];
    const int wv = t >> 6, lane = t & 63;
    const int c = lane * 4;
    float s0 = 0.f, s1 = 0.f, s2 = 0.f, s3 = 0.f;
    for (int r = beg + wv; r < end; r += 4) {
        const ushort4 vh = *(const ushort4*)&hh[(size_t)r * 256 + c];
        s0 += h2f(vh.x); s1 += h2f(vh.y); s2 += h2f(vh.z); s3 += h2f(vh.w);
    }
    sh[wv][lane][0] = s0; sh[wv][lane][1] = s1;
    sh[wv][lane][2] = s2; sh[wv][lane][3] = s3;
    __syncthreads();
    if (t < 64) {
        const float inv = 1.f / fmaxf((float)(end - beg), 1.f);
        float4 o;
        o.x = (sh[0][t][0] + sh[1][t][0] + sh[2][t][0] + sh[3][t][0]) * inv;
        o.y = (sh[0][t][1] + sh[1][t][1] + sh[2][t][1] + sh[3][t][1]) * inv;
        o.z = (sh[0][t][2] + sh[1][t][2] + sh[2][t][2] + sh[3][t][2]) * inv;
        o.w = (sh[0][t][3] + sh[1][t][3] + sh[2][t][3] + sh[3][t][3]) * inv;
        *(float4*)&pooled[(size_t)g * 256 + t * 4] = o;
    }
}

// Fused 3-layer classifier MLP: one block per graph.
__global__ __launch_bounds__(256)
void tg_mlp3(const float* __restrict__ pooled,
             const float* __restrict__ W0, const float* __restrict__ b0,
             const float* __restrict__ W1, const float* __restrict__ b1,
             const float* __restrict__ W2, const float* __restrict__ b2,
             float* __restrict__ out, int H2, int Cc)
{
    __shared__ float zin[256];
    __shared__ float z0[256];
    __shared__ float z1[256];
    const int g = blockIdx.x;
    const int t = threadIdx.x;
    zin[t] = pooled[(size_t)g * 256 + t];
    __syncthreads();
    float a = 0.f;
    for (int k = 0; k < 256; ++k) a += zin[k] * W0[(size_t)k * 256 + t];
    z0[t] = fmaxf(a + b0[t], 0.f);
    __syncthreads();
    if (t < H2) {
        float a1 = 0.f;
        for (int k = 0; k < 256; ++k) a1 += z0[k] * W1[(size_t)k * H2 + t];
        z1[t] = fmaxf(a1 + b1[t], 0.f);
    }
    __syncthreads();
    if (t < Cc) {
        float a2 = 0.f;
        for (int k = 0; k < H2; ++k) a2 += z1[k] * W2[(size_t)k * Cc + t];
        out[(size_t)g * Cc + t] = a2 + b2[t];
    }
}

extern "C" void kernel_launch(void* const* d_in, const int* in_sizes, int n_in,
                              void* d_out, int out_size, void* d_ws, size_t ws_size,
                              hipStream_t stream)
{
    const float* x    = (const float*)d_in[0];
    const float* W_ft = (const float*)d_in[1];
    const float* b_ft = (const float*)d_in[2];
    const float* ln_g = (const float*)d_in[3];
    const float* ln_b = (const float*)d_in[4];
    const float* W_g[3] = {(const float*)d_in[5], (const float*)d_in[7], (const float*)d_in[9]};
    const float* b_g[3] = {(const float*)d_in[6], (const float*)d_in[8], (const float*)d_in[10]};
    const float* W_c0 = (const float*)d_in[11];
    const float* b_c0 = (const float*)d_in[12];
    const float* W_c1 = (const float*)d_in[13];
    const float* b_c1 = (const float*)d_in[14];
    const float* W_c2 = (const float*)d_in[15];
    const float* b_c2 = (const float*)d_in[16];
    const int*   edge  = (const int*)d_in[17];
    const int*   batch = (const int*)d_in[18];

    const int N    = in_sizes[18];        // 100000
    const int E    = in_sizes[17] / 2;    // 1600000
    const int Mpad = (N + 127) & ~127;    // 100096
    const int H2   = in_sizes[14];        // 128
    const int Cc   = in_sizes[15] / H2;   // 4
    const int G    = out_size / Cc;       // 512

    const int* srcI = edge;
    const int* dstI = edge + E;

    size_t off = 0;
    auto alloc = [&](size_t bytes) {
        char* p = (char*)d_ws + off;
        off = (off + bytes + 255) & ~(size_t)255;
        return p;
    };
    unsigned short* hh    = (unsigned short*)alloc((size_t)Mpad * 256 * 2);
    unsigned short* hwpbA = (unsigned short*)alloc((size_t)Mpad * 256 * 2);
    unsigned short* hwpbB = (unsigned short*)alloc((size_t)Mpad * 256 * 2);
    float* dinv   = (float*)alloc((size_t)Mpad * 4);
    int*   deg    = (int*)alloc((size_t)Mpad * 4);
    int*   rowptr = (int*)alloc((size_t)(N + 1) * 4);
    int*   perm   = (int*)alloc((size_t)E * 4);
    int*   col    = (int*)alloc((size_t)E * 4);
    int*   bsums  = (int*)alloc(1024 * 4);
    float* pooled = (float*)alloc((size_t)G * 256 * 4);
    unsigned short* Bt[4];
    for (int i = 0; i < 4; ++i)
        Bt[i] = (unsigned short*)alloc((size_t)256 * 512 * 2);
    (void)ws_size; (void)n_in;

    hipMemsetAsync(deg, 0, (size_t)Mpad * 4, stream);
    // zero pad rows of h plane (read by layer-1 GEMM A staging)
    hipMemsetAsync(hh + (size_t)N * 256, 0, (size_t)(Mpad - N) * 256 * 2, stream);

    // 0. weight prep
    tg_splitB<<<dim3(4, 4, 4), dim3(256), 0, stream>>>(
        W_ft, W_g[0], W_g[1], W_g[2], Bt[0], Bt[1], Bt[2], Bt[3]);

    // 1. fused feature transform + LayerNorm + PE -> single f16 h plane
    tg_ft_ln<<<dim3(Mpad / 128), dim3(256), 0, stream>>>(
        x, Bt[0], b_ft, ln_g, ln_b, hh, N);

    // 2. degrees + CSR build (rows = dst, cols = src)
    tg_count<<<dim3((E + 255) / 256), dim3(256), 0, stream>>>(dstI, deg, perm, E);
    tg_dinv<<<dim3((Mpad + 255) / 256), dim3(256), 0, stream>>>(deg, dinv, Mpad);
    const int NB = (N + 1023) / 1024;
    tg_scan1<<<dim3(NB), dim3(1024), 0, stream>>>(deg, rowptr, bsums, N);
    tg_scan2<<<dim3(1), dim3(1024), 0, stream>>>(bsums, NB);
    tg_scan3<<<dim3((N + 1024) / 1024), dim3(1024), 0, stream>>>(rowptr, bsums, N, E);
    tg_fill<<<dim3((E + 255) / 256), dim3(256), 0, stream>>>(srcI, dstI, rowptr, perm, col, E);

    // 3. GCN layers: gemm1 standalone; layers 2,3 fused (agg_l + gemm_{l+1});
    //    final aggregate standalone -> hh
    const int nbx = (Mpad / 128) * 2;
    tg_gemm<<<dim3(nbx), dim3(256), 0, stream>>>(hh, Bt[1], dinv, hwpbA);
    const int nfb = Mpad / 64;
    tg_agg_gemm<<<dim3(nfb), dim3(256), 0, stream>>>(hwpbA, rowptr, col, dinv,
                                                     b_g[0], Bt[2], hwpbB, N);
    tg_agg_gemm<<<dim3(nfb), dim3(256), 0, stream>>>(hwpbB, rowptr, col, dinv,
                                                     b_g[1], Bt[3], hwpbA, N);
    tg_aggregate_h<<<dim3((N + 7) / 8), dim3(256), 0, stream>>>(hwpbA, rowptr, col, dinv,
                                                                b_g[2], hh, N);

    // 4. per-graph mean pool (ranges inlined)
    tg_pool<<<dim3(G), dim3(256), 0, stream>>>(hh, batch, pooled, N, G);

    // 5. fused classifier MLP
    tg_mlp3<<<dim3(G), dim3(256), 0, stream>>>(pooled, W_c0, b_c0, W_c1, b_c1,
                                               W_c2, b_c2, (float*)d_out, H2, Cc);
}